// Round 13
// baseline (219.008 us; speedup 1.0000x reference)
//
#include <hip/hip_runtime.h>
#include <hip/hip_bf16.h>
#include <math.h>

#define DIMC 128
#define CS2L (0.08838834764831845f * 1.4426950408889634f)   // (1/sqrt(128))*log2(e)
#define HBLK 512   // histogram blocks inside prep (64 threads each)

typedef __attribute__((ext_vector_type(8))) short short8;
typedef __attribute__((ext_vector_type(4))) float floatx4;
typedef __attribute__((ext_vector_type(2))) float f32x2;

// bf16 helpers
static __device__ __forceinline__ unsigned pk2(float lo, float hi) {
    __hip_bfloat162 h = __float22bfloat162_rn(make_float2(lo, hi));  // v_cvt_pk_bf16_f32
    return *(unsigned*)&h;
}
static __device__ __forceinline__ unsigned short f2bf(float x) {
    union { float f; unsigned int u; } v; v.f = x;
    unsigned int r = v.u + 0x7FFFu + ((v.u >> 16) & 1u);
    return (unsigned short)(r >> 16);
}
// unpack packed bf16x2 -> float2 (low, high)
static __device__ __forceinline__ f32x2 bfp(unsigned int u) {
    union { unsigned int i; float f; } a, b;
    a.i = u << 16; b.i = u & 0xFFFF0000u;
    f32x2 r; r.x = a.f; r.y = b.f; return r;
}

// DPP-based add across lanes (mirror levels valid because groups become equal-valued)
template<int CTRL>
static __device__ __forceinline__ float dpp_add(float x) {
    int y = __builtin_amdgcn_update_dpp(0, __float_as_int(x), CTRL, 0xF, 0xF, true);
    return x + __int_as_float(y);
}
// 16-lane sum (all lanes of each 16-group get the total) — pure DPP, no LDS pipe
static __device__ __forceinline__ float red16(float p) {
    p = dpp_add<0xB1>(p);    // quad_perm xor1
    p = dpp_add<0x4E>(p);    // quad_perm xor2
    p = dpp_add<0x141>(p);   // row_half_mirror (xor4-equiv once quads equal)
    p = dpp_add<0x140>(p);   // row_mirror      (xor8-equiv once groups-of-8 equal)
    return p;
}

// ---------------- fused prep: W fragments (6 mats) + TypeEmb + edge histogram --------------
struct PrepArgs {
    const float* W[6];
    unsigned short* F[6];
    float wscale[6];
    const float* relemb; const float* selfrel;
    float* TypeEmb;
    const int* edst;
    int* deg;
    int E;
    int R; int N;
};

__global__ __launch_bounds__(64) void prep_all(PrepArgs a)
{
    int b = blockIdx.x;
    int lane = threadIdx.x;
    if (b < 192) {                       // fragment build
        int mat = b >> 5, ts = b & 31;
        int s = ts & 3, t = ts >> 2;
        int q = lane >> 4, c = lane & 15;
        const float* W = a.W[mat];
        float sc = a.wscale[mat];
        unsigned short o[8];
        #pragma unroll
        for (int j = 0; j < 8; ++j)
            o[j] = f2bf(W[(long)(s * 32 + q * 8 + j) * DIMC + t * 16 + c] * sc);
        uint4 u;
        u.x = (unsigned)o[0] | ((unsigned)o[1] << 16);
        u.y = (unsigned)o[2] | ((unsigned)o[3] << 16);
        u.z = (unsigned)o[4] | ((unsigned)o[5] << 16);
        u.w = (unsigned)o[6] | ((unsigned)o[7] << 16);
        ((uint4*)a.F[mat])[ts * 64 + lane] = u;
    } else if (b < 192 + a.R + 1) {      // TypeEmb row copy (f32)
        int r = b - 192;
        const float* src = (r < a.R) ? (a.relemb + (long)r * DIMC) : a.selfrel;
        float2 v = ((const float2*)src)[lane];
        ((float2*)(a.TypeEmb + (long)r * DIMC))[lane] = v;
    } else {                              // edge histogram (deg pre-zeroed via memset)
        int i = (b - (192 + a.R + 1)) * 64 + lane;
        int stride = HBLK * 64;
        for (; i < a.E; i += stride) atomicAdd(&a.deg[a.edst[i]], 1);
    }
}

// ---------------- MFMA GEMM: y=0 Q(bf16), y=1 fused K+V, y=2/3 QK, y=4 scatter ------------
struct GemmM5 {
    const float*          Af[5];
    const unsigned short* Ab[5];
    const unsigned short* F[5];
    const float*          bias[5];
    float                 bscale[5];
    float*                outf[5];
    unsigned short*       outb[5];
    int                   ostride[5];
    int                   ooff[5];
    int                   M[5];
    const unsigned short* F2;      // Wv fragments (KV slice)
    const float*          bias2;   // bv
    unsigned short*       outb2;   // Vb
    const int*            sc_src;  // scatter slice args
    const int*            sc_dst;
    const int*            sc_typ;
    int*                  sc_cursor;
    int2*                 sc_sedge;
    int                   sc_E;
};

__global__ __launch_bounds__(256) void gemm_mfma(GemmM5 g)
{
    __shared__ uint4 wlds[2048];  // 32KB weight fragment table

    if (blockIdx.y == 4) {        // scatter slice: grid-strided, overlaps the GEMM slices
        int i = blockIdx.x * blockDim.x + threadIdx.x;
        int stride = gridDim.x * blockDim.x;
        for (; i < g.sc_E; i += stride) {
            int d = g.sc_dst[i];
            int p = atomicAdd(&g.sc_cursor[d], 1);
            g.sc_sedge[p] = make_int2(g.sc_src[i] << 8, g.sc_typ[i] << 9);
        }
        return;
    }

    const int wave = threadIdx.x >> 6;
    const int lane = threadIdx.x & 63;
    const int q = lane >> 4, c = lane & 15;

    if (blockIdx.y == 1) {        // fused K+V projection (A = last, loaded once)
        const int M = g.M[1];
        if ((int)blockIdx.x * 64 >= M) return;
        const int rowbase = blockIdx.x * 64 + wave * 16;

        {
            const uint4* Fp = (const uint4*)g.F[1];
            #pragma unroll
            for (int j = 0; j < 8; ++j)
                wlds[threadIdx.x + j * 256] = Fp[threadIdx.x + j * 256];
        }
        int rowA = rowbase + c; if (rowA > M - 1) rowA = M - 1;
        short8 af[4];
        {
            const float* Ar = g.Af[1] + (long)rowA * DIMC + q * 8;
            #pragma unroll
            for (int s = 0; s < 4; ++s) {
                float4 x0 = *(const float4*)(Ar + s * 32);
                float4 x1 = *(const float4*)(Ar + s * 32 + 4);
                uint4 u;
                u.x = pk2(x0.x, x0.y);
                u.y = pk2(x0.z, x0.w);
                u.z = pk2(x1.x, x1.y);
                u.w = pk2(x1.z, x1.w);
                af[s] = *(short8*)&u;
            }
        }
        floatx4 acc[8];
        #pragma unroll
        for (int t = 0; t < 8; ++t) acc[t] = (floatx4){0.f, 0.f, 0.f, 0.f};
        __syncthreads();
        #pragma unroll
        for (int t = 0; t < 8; ++t)
            #pragma unroll
            for (int s = 0; s < 4; ++s) {
                uint4 u = wlds[(t * 4 + s) * 64 + lane];
                acc[t] = __builtin_amdgcn_mfma_f32_16x16x32_bf16(af[s], *(short8*)&u, acc[t], 0, 0, 0);
            }
        __syncthreads();
        {
            const uint4* Fp = (const uint4*)g.F2;
            #pragma unroll
            for (int j = 0; j < 8; ++j)
                wlds[threadIdx.x + j * 256] = Fp[threadIdx.x + j * 256];
        }
        #pragma unroll
        for (int t = 0; t < 8; ++t)
            #pragma unroll
            for (int r = 0; r < 4; ++r) {
                float other = __shfl_xor(acc[t][r], 1);
                int row = rowbase + q * 4 + r;
                if ((lane & 1) == 0 && row < M)
                    ((unsigned*)g.outb[1])[(long)row * 64 + t * 8 + (c >> 1)] = pk2(acc[t][r], other);
            }
        #pragma unroll
        for (int t = 0; t < 8; ++t) {
            float b = g.bias2[t * 16 + c];
            acc[t] = (floatx4){b, b, b, b};
        }
        __syncthreads();
        #pragma unroll
        for (int t = 0; t < 8; ++t)
            #pragma unroll
            for (int s = 0; s < 4; ++s) {
                uint4 u = wlds[(t * 4 + s) * 64 + lane];
                acc[t] = __builtin_amdgcn_mfma_f32_16x16x32_bf16(af[s], *(short8*)&u, acc[t], 0, 0, 0);
            }
        #pragma unroll
        for (int t = 0; t < 8; ++t)
            #pragma unroll
            for (int r = 0; r < 4; ++r) {
                float other = __shfl_xor(acc[t][r], 1);
                int row = rowbase + q * 4 + r;
                if ((lane & 1) == 0 && row < M)
                    ((unsigned*)g.outb2)[(long)row * 64 + t * 8 + (c >> 1)] = pk2(acc[t][r], other);
            }
        return;
    }

    const int which = blockIdx.y;
    const int M = g.M[which];
    if ((int)blockIdx.x * 64 >= M) return;

    const float*          __restrict__ Af   = g.Af[which];
    const unsigned short* __restrict__ Ab   = g.Ab[which];
    const unsigned short* __restrict__ F    = g.F[which];
    const float*          __restrict__ bias = g.bias[which];
    const float bsc = g.bscale[which];
    float*          __restrict__ outf = g.outf[which];
    unsigned short* __restrict__ outb = g.outb[which];
    const int ostride = g.ostride[which];
    const int ooff    = g.ooff[which];
    const int rowbase = blockIdx.x * 64 + wave * 16;

    {
        const uint4* Fp = (const uint4*)F;
        #pragma unroll
        for (int j = 0; j < 8; ++j)
            wlds[threadIdx.x + j * 256] = Fp[threadIdx.x + j * 256];
    }

    int rowA = rowbase + c; if (rowA > M - 1) rowA = M - 1;
    short8 af[4];
    if (Af) {
        const float* Ar = Af + (long)rowA * DIMC + q * 8;
        #pragma unroll
        for (int s = 0; s < 4; ++s) {
            float4 x0 = *(const float4*)(Ar + s * 32);
            float4 x1 = *(const float4*)(Ar + s * 32 + 4);
            uint4 u;
            u.x = pk2(x0.x, x0.y);
            u.y = pk2(x0.z, x0.w);
            u.z = pk2(x1.x, x1.y);
            u.w = pk2(x1.z, x1.w);
            af[s] = *(short8*)&u;
        }
    } else {
        const unsigned short* Ar = Ab + (long)rowA * DIMC + q * 8;
        #pragma unroll
        for (int s = 0; s < 4; ++s) {
            uint4 u = *(const uint4*)(Ar + s * 32);
            af[s] = *(short8*)&u;
        }
    }

    floatx4 acc[8];
    #pragma unroll
    for (int t = 0; t < 8; ++t) {
        float b = bias ? bias[t * 16 + c] * bsc : 0.0f;
        acc[t] = (floatx4){b, b, b, b};
    }

    __syncthreads();

    #pragma unroll
    for (int t = 0; t < 8; ++t)
        #pragma unroll
        for (int s = 0; s < 4; ++s) {
            uint4 u = wlds[(t * 4 + s) * 64 + lane];
            acc[t] = __builtin_amdgcn_mfma_f32_16x16x32_bf16(af[s], *(short8*)&u, acc[t], 0, 0, 0);
        }

    if (outf) {
        #pragma unroll
        for (int t = 0; t < 8; ++t)
            #pragma unroll
            for (int r = 0; r < 4; ++r) {
                int row = rowbase + q * 4 + r;
                if (row < M)
                    outf[(long)row * DIMC + t * 16 + c] = acc[t][r];
            }
    } else {
        #pragma unroll
        for (int t = 0; t < 8; ++t)
            #pragma unroll
            for (int r = 0; r < 4; ++r) {
                float other = __shfl_xor(acc[t][r], 1);
                int row = rowbase + q * 4 + r;
                if ((lane & 1) == 0 && row < M) {
                    unsigned word = pk2(acc[t][r], other);
                    ((unsigned*)outb)[((long)row * 64 + t * 8 + (c >> 1))
                                      * (long)ostride + ooff] = word;
                }
            }
    }
}

// ---------------- CSR build ----------------
__global__ __launch_bounds__(256) void partial_sums(const int* __restrict__ deg,
                                                    int* __restrict__ partial, int N)
{
    __shared__ int sh[256];
    int t = threadIdx.x;
    int beg = blockIdx.x * 1024 + t * 4;
    int s = 0;
    if (beg + 3 < N) { int4 v = *(const int4*)(deg + beg); s = v.x + v.y + v.z + v.w; }
    else { for (int j = 0; j < 4; ++j) if (beg + j < N) s += deg[beg + j]; }
    sh[t] = s;
    __syncthreads();
    for (int d = 128; d >= 1; d >>= 1) {
        if (t < d) sh[t] += sh[t + d];
        __syncthreads();
    }
    if (t == 0) partial[blockIdx.x] = sh[0];
}

__global__ __launch_bounds__(256) void scan_write_offsets(const int* __restrict__ deg,
                                                          const int* __restrict__ partial,
                                                          int* __restrict__ offs,
                                                          int* __restrict__ cursor, int N, int nb)
{
    __shared__ int sh[256];
    __shared__ int sbase;
    int t = threadIdx.x;
    if (t < 64) {
        int v = (t < nb && t < (int)blockIdx.x) ? partial[t] : 0;
        #pragma unroll
        for (int d = 32; d >= 1; d >>= 1) v += __shfl_xor(v, d);
        if (t == 0) sbase = v;
    }
    int beg = blockIdx.x * 1024 + t * 4;
    int d0 = 0, d1 = 0, d2 = 0, d3 = 0;
    if (beg + 3 < N) { int4 v = *(const int4*)(deg + beg); d0 = v.x; d1 = v.y; d2 = v.z; d3 = v.w; }
    else {
        if (beg < N)     d0 = deg[beg];
        if (beg + 1 < N) d1 = deg[beg + 1];
        if (beg + 2 < N) d2 = deg[beg + 2];
        if (beg + 3 < N) d3 = deg[beg + 3];
    }
    int s = d0 + d1 + d2 + d3;
    sh[t] = s;
    __syncthreads();
    for (int d = 1; d < 256; d <<= 1) {
        int v = (t >= d) ? sh[t - d] : 0;
        __syncthreads();
        sh[t] += v;
        __syncthreads();
    }
    int base = sbase + sh[t] - s;
    int o0 = base, o1 = o0 + d0, o2 = o1 + d1, o3 = o2 + d2;
    if (beg < N)     { offs[beg]     = o0; cursor[beg]     = o0; }
    if (beg + 1 < N) { offs[beg + 1] = o1; cursor[beg + 1] = o1; }
    if (beg + 2 < N) { offs[beg + 2] = o2; cursor[beg + 2] = o2; }
    if (beg + 3 < N) { offs[beg + 3] = o3; cursor[beg + 3] = o3; }
}

// ---------------- per-node dual softmax + V aggregation ----------------
// wave = 1 node; QUARTER-wave (16 lanes) = 1 edge, lane owns 8 dims.
// One fully-coalesced 16B instruction per K/V table per edge; QK = 2x16B.
// Depth-1 sedge prefetch (8B) cuts the per-iter serial chain front.
// Self-loop = virtual edge at index dcnt. Q stored bf16 pre-scaled to exp2 domain.
__global__ __launch_bounds__(256) void node_kernel(
    const char*  __restrict__ Qb,     // row n at byte n<<8 (bf16); lane ql: 16B at ql<<4
    const char*  __restrict__ Kb,     // row n at byte n<<8; lane ql: 16B at ql<<4
    const char*  __restrict__ Vb,     // same layout as Kb
    const char*  __restrict__ QKb,    // row t at byte t<<9; lane ql: 32B at ql<<5
    const int* __restrict__ offs, const int* __restrict__ deg,
    const int2* __restrict__ sedge,   // (src<<8, type<<9)
    float* __restrict__ out_sta, uint4* __restrict__ feat_dyn,
    int N, int R)
{
    int n = (blockIdx.x * blockDim.x + threadIdx.x) >> 6;
    int lane = threadIdx.x & 63;
    if (n >= N) return;
    const int ql = lane & 15;    // lane within quarter
    const int qt = lane >> 4;    // quarter id (edge stream)
    const int lo16 = ql << 4;
    const int lo32 = ql << 5;

    int base = offs[n];
    int dcnt = deg[n];
    int etot = dcnt + 1;             // + virtual self edge at index dcnt

    // q dims 8ql..8ql+7 from bf16 row (pre-scaled)
    f32x2 qr0, qr1, qr2, qr3;
    {
        uint4 qw = *(const uint4*)(Qb + ((long)n << 8) + lo16);
        qr0 = bfp(qw.x); qr1 = bfp(qw.y); qr2 = bfp(qw.z); qr3 = bfp(qw.w);
    }

    float s_d = 0.0f, s_s = 0.0f;
    f32x2 accd0 = {0.f, 0.f}, accd1 = accd0, accd2 = accd0, accd3 = accd0;
    f32x2 accs0 = accd0, accs1 = accd0, accs2 = accd0, accs3 = accd0;

    const int2 eself = make_int2(n << 8, R << 9);

    int T = (etot + 3) >> 2;
    int2 eCur = eself;
    {
        int i = qt;
        if (i < dcnt) eCur = sedge[base + i];
    }
    for (int it = 0; it < T; ++it) {
        int i = 4 * it + qt;
        bool vv = i < etot;

        int2 eNxt = eself;
        if (it + 1 < T) {
            int inx = 4 * (it + 1) + qt;
            if (inx < dcnt) eNxt = sedge[base + inx];
        }

        uint4 kx  = *(const uint4*)(Kb + eCur.x + lo16);
        uint4 vx  = *(const uint4*)(Vb + eCur.x + lo16);
        uint4 qk0 = *(const uint4*)(QKb + eCur.y + lo32);
        uint4 qk1 = *(const uint4*)(QKb + eCur.y + lo32 + 16);

        f32x2 dp;
        dp  = (qr0 + bfp(qk0.x)) * (bfp(kx.x) + bfp(qk0.y));
        dp += (qr1 + bfp(qk0.z)) * (bfp(kx.y) + bfp(qk0.w));
        dp += (qr2 + bfp(qk1.x)) * (bfp(kx.z) + bfp(qk1.y));
        dp += (qr3 + bfp(qk1.z)) * (bfp(kx.w) + bfp(qk1.w));
        float p = red16(dp.x + dp.y);

        float wd = vv ? exp2f(p)  : 0.0f;
        float ws = vv ? exp2f(-p) : 0.0f;
        s_d += wd; s_s += ws;

        f32x2 v0 = bfp(vx.x), v1 = bfp(vx.y), v2 = bfp(vx.z), v3 = bfp(vx.w);
        accd0 += v0 * wd; accd1 += v1 * wd; accd2 += v2 * wd; accd3 += v3 * wd;
        accs0 += v0 * ws; accs1 += v1 * ws; accs2 += v2 * ws; accs3 += v3 * ws;

        eCur = eNxt;
    }

    // ---- merge quarters (plain sums; dims align across quarters via ql) ----
    #define MRG(x) { x += __shfl_xor(x, 16); x += __shfl_xor(x, 32); }
    MRG(s_d) MRG(s_s)
    MRG(accd0.x) MRG(accd0.y) MRG(accd1.x) MRG(accd1.y)
    MRG(accd2.x) MRG(accd2.y) MRG(accd3.x) MRG(accd3.y)
    MRG(accs0.x) MRG(accs0.y) MRG(accs1.x) MRG(accs1.y)
    MRG(accs2.x) MRG(accs2.y) MRG(accs3.x) MRG(accs3.y)
    #undef MRG

    if (qt == 0) {
        float denom = (float)(dcnt + 1);
        float id_ = 1.0f / (s_d * denom);
        float is_ = 1.0f / (s_s * denom);
        float4* op = (float4*)(out_sta + (long)n * DIMC + ql * 8);
        op[0] = make_float4(accs0.x * is_, accs0.y * is_, accs1.x * is_, accs1.y * is_);
        op[1] = make_float4(accs2.x * is_, accs2.y * is_, accs3.x * is_, accs3.y * is_);
        uint4 w;
        w.x = pk2(accd0.x * id_, accd0.y * id_);
        w.y = pk2(accd1.x * id_, accd1.y * id_);
        w.z = pk2(accd2.x * id_, accd2.y * id_);
        w.w = pk2(accd3.x * id_, accd3.y * id_);
        feat_dyn[(unsigned)n * 16u + ql] = w;
    }
}

// ---------------- launch ----------------
extern "C" void kernel_launch(void* const* d_in, const int* in_sizes, int n_in,
                              void* d_out, int out_size, void* d_ws, size_t ws_size,
                              hipStream_t stream)
{
    const float* curr    = (const float*)d_in[0];
    const float* last    = (const float*)d_in[1];
    const float* relemb  = (const float*)d_in[2];
    const float* selfrel = (const float*)d_in[3];
    const float* Wq      = (const float*)d_in[4];
    const float* bq      = (const float*)d_in[5];
    const float* Wk      = (const float*)d_in[6];
    const float* bk      = (const float*)d_in[7];
    const float* Wv      = (const float*)d_in[8];
    const float* bv      = (const float*)d_in[9];
    const float* dynw    = (const float*)d_in[10];
    const int*   eidx    = (const int*)d_in[11];
    const int*   etype   = (const int*)d_in[12];
    float* out = (float*)d_out;

    const int N = in_sizes[0] / DIMC;   // 40000
    const int E = in_sizes[12];         // 400000
    const int R = in_sizes[2] / DIMC;   // 502
    const int* esrc = eidx;
    const int* edst = eidx + E;

    char* wp = (char*)d_ws;
    auto alloc = [&](size_t bytes) { char* r = wp; wp += (bytes + 15) & ~(size_t)15; return r; };
    size_t nd = (size_t)N * DIMC;
    unsigned short* Qb    = (unsigned short*)alloc((size_t)N * 256);
    unsigned short* Kb    = (unsigned short*)alloc((size_t)N * 256);
    unsigned short* Vb    = (unsigned short*)alloc((size_t)N * 256);
    unsigned short* Fdb   = (unsigned short*)alloc(nd * 2);
    uint4*          QKre  = (uint4*)alloc((size_t)(R + 1) * 32 * 16);
    float*          TypeEmb = (float*)alloc((size_t)(R + 2) * DIMC * 4);
    unsigned short* FW[6];
    for (int m = 0; m < 6; ++m) FW[m] = (unsigned short*)alloc(2048 * 8 * 2);
    int*            deg   = (int*)alloc((size_t)N * 4);
    int*            offs  = (int*)alloc((size_t)N * 4);
    int*            cursor= (int*)alloc((size_t)N * 4);
    int2*           sedge = (int2*)alloc((size_t)E * 8);
    int*            partial = (int*)alloc(256 * 4);

    const int gblk = N / 64;                 // 625
    const int sblk = (N + 1023) / 1024;      // 40

    // 0. zero deg (histogram runs inside prep)
    hipMemsetAsync(deg, 0, (size_t)N * 4, stream);

    // 1. fused prep: W fragments + TypeEmb + edge histogram
    PrepArgs pa;
    pa.W[0] = Wq;   pa.W[1] = Wk;   pa.W[2] = Wv;
    pa.W[3] = dynw; pa.W[4] = Wq + (size_t)DIMC * DIMC; pa.W[5] = Wk + (size_t)DIMC * DIMC;
    pa.wscale[0] = CS2L; pa.wscale[1] = 1.0f; pa.wscale[2] = 1.0f;
    pa.wscale[3] = 1.0f; pa.wscale[4] = CS2L; pa.wscale[5] = 1.0f;
    for (int m = 0; m < 6; ++m) pa.F[m] = FW[m];
    pa.relemb = relemb; pa.selfrel = selfrel; pa.TypeEmb = TypeEmb;
    pa.edst = edst; pa.deg = deg; pa.E = E; pa.R = R; pa.N = N;
    int pgrid = 192 + (R + 1) + HBLK;
    hipLaunchKernelGGL(prep_all, dim3(pgrid), dim3(64), 0, stream, pa);

    // 2. CSR offsets (needs deg only)
    hipLaunchKernelGGL(partial_sums, dim3(sblk), dim3(256), 0, stream, deg, partial, N);
    hipLaunchKernelGGL(scan_write_offsets, dim3(sblk), dim3(256), 0, stream,
                       deg, partial, offs, cursor, N, sblk);

    // 3. projections + scatter in ONE dispatch (scatter latency hides under the GEMM)
    GemmM5 g5;
    for (int s = 0; s < 5; ++s) { g5.Af[s] = nullptr; g5.Ab[s] = nullptr; g5.outf[s] = nullptr; g5.outb[s] = nullptr; g5.bias[s] = nullptr; g5.bscale[s] = 1.0f; g5.ostride[s] = 1; g5.ooff[s] = 0; g5.M[s] = 0; }
    g5.Af[0] = curr;    g5.F[0] = FW[0]; g5.outb[0] = Qb;  g5.M[0] = N;
    g5.Af[1] = last;    g5.F[1] = FW[1]; g5.outb[1] = Kb;  g5.M[1] = N;
    g5.F2 = FW[2]; g5.bias2 = bv; g5.outb2 = Vb;
    g5.Af[2] = TypeEmb; g5.F[2] = FW[4]; g5.bias[2] = bq;  g5.outb[2] = (unsigned short*)QKre;
    g5.ostride[2] = 2;  g5.ooff[2] = 0;  g5.M[2] = R + 1;  g5.bscale[2] = CS2L;
    g5.Af[3] = TypeEmb; g5.F[3] = FW[5]; g5.bias[3] = bk;  g5.outb[3] = (unsigned short*)QKre;
    g5.ostride[3] = 2;  g5.ooff[3] = 1;  g5.M[3] = R + 1;
    g5.sc_src = esrc; g5.sc_dst = edst; g5.sc_typ = etype;
    g5.sc_cursor = cursor; g5.sc_sedge = sedge; g5.sc_E = E;
    hipLaunchKernelGGL(gemm_mfma, dim3(gblk, 5), dim3(256), 0, stream, g5);

    // 4. node aggregation (4 nodes per 256-thread block; quarter-wave per edge)
    hipLaunchKernelGGL(node_kernel, dim3((N + 3) / 4), dim3(256), 0, stream,
                       (const char*)Qb, (const char*)Kb, (const char*)Vb, (const char*)QKre,
                       offs, deg, sedge, out, (uint4*)Fdb, N, R);

    // 5. final GEMM: feat_dyn @ dyn_weight
    GemmM5 gf;
    for (int s = 0; s < 5; ++s) { gf.Af[s] = nullptr; gf.Ab[s] = nullptr; gf.outf[s] = nullptr; gf.outb[s] = nullptr; gf.bias[s] = nullptr; gf.bscale[s] = 1.0f; gf.ostride[s] = 1; gf.ooff[s] = 0; gf.M[s] = 0; }
    gf.Ab[0] = Fdb; gf.F[0] = FW[3]; gf.outf[0] = out + nd; gf.M[0] = N;
    gf.F2 = FW[2]; gf.bias2 = bv; gf.outb2 = Vb;
    gf.sc_src = esrc; gf.sc_dst = edst; gf.sc_typ = etype;
    gf.sc_cursor = cursor; gf.sc_sedge = sedge; gf.sc_E = 0;
    hipLaunchKernelGGL(gemm_mfma, dim3(gblk, 1), dim3(256), 0, stream, gf);
}

// Round 14
// 209.606 us; speedup vs baseline: 1.0449x; 1.0449x over previous
//
#include <hip/hip_runtime.h>
#include <hip/hip_bf16.h>
#include <math.h>

#define DIMC 128
#define CS2L (0.08838834764831845f * 1.4426950408889634f)   // (1/sqrt(128))*log2(e)

typedef __attribute__((ext_vector_type(8))) short short8;
typedef __attribute__((ext_vector_type(4))) float floatx4;
typedef __attribute__((ext_vector_type(2))) float f32x2;

// bf16 helpers
static __device__ __forceinline__ unsigned pk2(float lo, float hi) {
    __hip_bfloat162 h = __float22bfloat162_rn(make_float2(lo, hi));  // v_cvt_pk_bf16_f32
    return *(unsigned*)&h;
}
static __device__ __forceinline__ unsigned short f2bf(float x) {
    union { float f; unsigned int u; } v; v.f = x;
    unsigned int r = v.u + 0x7FFFu + ((v.u >> 16) & 1u);
    return (unsigned short)(r >> 16);
}
// unpack packed bf16x2 -> float2 (low, high)
static __device__ __forceinline__ f32x2 bfp(unsigned int u) {
    union { unsigned int i; float f; } a, b;
    a.i = u << 16; b.i = u & 0xFFFF0000u;
    f32x2 r; r.x = a.f; r.y = b.f; return r;
}

// DPP-based add across lanes (mirror levels valid because groups become equal-valued)
template<int CTRL>
static __device__ __forceinline__ float dpp_add(float x) {
    int y = __builtin_amdgcn_update_dpp(0, __float_as_int(x), CTRL, 0xF, 0xF, true);
    return x + __int_as_float(y);
}
// 16-lane sum (all lanes of each 16-group get the total) — pure DPP, no LDS pipe
static __device__ __forceinline__ float red16(float p) {
    p = dpp_add<0xB1>(p);    // quad_perm xor1
    p = dpp_add<0x4E>(p);    // quad_perm xor2
    p = dpp_add<0x141>(p);   // row_half_mirror (xor4-equiv once quads equal)
    p = dpp_add<0x140>(p);   // row_mirror      (xor8-equiv once groups-of-8 equal)
    return p;
}

// ---------------- fused prep: W fragments (6 mats) + TypeEmb staging + deg zero -------------
struct PrepArgs {
    const float* W[6];
    unsigned short* F[6];
    float wscale[6];
    const float* relemb; const float* selfrel;
    float* TypeEmb;
    int* deg;
    int R; int N;
};

__global__ __launch_bounds__(64) void prep_all(PrepArgs a)
{
    int b = blockIdx.x;
    int lane = threadIdx.x;
    if (b < 192) {                       // fragment build
        int mat = b >> 5, ts = b & 31;
        int s = ts & 3, t = ts >> 2;
        int q = lane >> 4, c = lane & 15;
        const float* W = a.W[mat];
        float sc = a.wscale[mat];
        unsigned short o[8];
        #pragma unroll
        for (int j = 0; j < 8; ++j)
            o[j] = f2bf(W[(long)(s * 32 + q * 8 + j) * DIMC + t * 16 + c] * sc);
        uint4 u;
        u.x = (unsigned)o[0] | ((unsigned)o[1] << 16);
        u.y = (unsigned)o[2] | ((unsigned)o[3] << 16);
        u.z = (unsigned)o[4] | ((unsigned)o[5] << 16);
        u.w = (unsigned)o[6] | ((unsigned)o[7] << 16);
        ((uint4*)a.F[mat])[ts * 64 + lane] = u;
    } else if (b < 192 + a.R + 1) {      // TypeEmb row copy (f32)
        int r = b - 192;
        const float* src = (r < a.R) ? (a.relemb + (long)r * DIMC) : a.selfrel;
        float2 v = ((const float2*)src)[lane];
        ((float2*)(a.TypeEmb + (long)r * DIMC))[lane] = v;
    } else {                              // deg zero
        int i = (b - (192 + a.R + 1)) * 64 + lane;
        if (i < a.N) a.deg[i] = 0;
    }
}

// ---------------- MFMA GEMM: y=0 Q(bf16 out), y=1 fused K+V, y=2/3 QK, y=4 hist -----------
struct GemmM5 {
    const float*          Af[5];
    const unsigned short* Ab[5];
    const unsigned short* F[5];
    const float*          bias[5];
    float                 bscale[5];
    float*                outf[5];
    unsigned short*       outb[5];
    int                   ostride[5];
    int                   ooff[5];
    int                   M[5];
    const unsigned short* F2;      // Wv fragments (KV slice)
    const float*          bias2;   // bv
    unsigned short*       outb2;   // Vb
    const int*            hist_dst;
    int*                  hist_deg;
    int                   hist_E;
};

__global__ __launch_bounds__(256) void gemm_mfma(GemmM5 g)
{
    __shared__ uint4 wlds[2048];  // 32KB weight fragment table

    if (blockIdx.y == 4) {        // histogram slice, grid-strided device atomics (free-rides)
        int i = blockIdx.x * blockDim.x + threadIdx.x;
        int stride = gridDim.x * blockDim.x;
        for (; i < g.hist_E; i += stride) atomicAdd(&g.hist_deg[g.hist_dst[i]], 1);
        return;
    }

    const int wave = threadIdx.x >> 6;
    const int lane = threadIdx.x & 63;
    const int q = lane >> 4, c = lane & 15;

    if (blockIdx.y == 1) {        // fused K+V projection (A = last, loaded once)
        const int M = g.M[1];
        if ((int)blockIdx.x * 64 >= M) return;
        const int rowbase = blockIdx.x * 64 + wave * 16;

        {
            const uint4* Fp = (const uint4*)g.F[1];
            #pragma unroll
            for (int j = 0; j < 8; ++j)
                wlds[threadIdx.x + j * 256] = Fp[threadIdx.x + j * 256];
        }
        int rowA = rowbase + c; if (rowA > M - 1) rowA = M - 1;
        short8 af[4];
        {
            const float* Ar = g.Af[1] + (long)rowA * DIMC + q * 8;
            #pragma unroll
            for (int s = 0; s < 4; ++s) {
                float4 x0 = *(const float4*)(Ar + s * 32);
                float4 x1 = *(const float4*)(Ar + s * 32 + 4);
                uint4 u;
                u.x = pk2(x0.x, x0.y);
                u.y = pk2(x0.z, x0.w);
                u.z = pk2(x1.x, x1.y);
                u.w = pk2(x1.z, x1.w);
                af[s] = *(short8*)&u;
            }
        }
        floatx4 acc[8];
        #pragma unroll
        for (int t = 0; t < 8; ++t) acc[t] = (floatx4){0.f, 0.f, 0.f, 0.f};
        __syncthreads();
        #pragma unroll
        for (int t = 0; t < 8; ++t)
            #pragma unroll
            for (int s = 0; s < 4; ++s) {
                uint4 u = wlds[(t * 4 + s) * 64 + lane];
                acc[t] = __builtin_amdgcn_mfma_f32_16x16x32_bf16(af[s], *(short8*)&u, acc[t], 0, 0, 0);
            }
        __syncthreads();   // all waves done reading Wk
        {
            const uint4* Fp = (const uint4*)g.F2;
            #pragma unroll
            for (int j = 0; j < 8; ++j)
                wlds[threadIdx.x + j * 256] = Fp[threadIdx.x + j * 256];
        }
        // K epilogue (bf16 rows, 256B)
        #pragma unroll
        for (int t = 0; t < 8; ++t)
            #pragma unroll
            for (int r = 0; r < 4; ++r) {
                float other = __shfl_xor(acc[t][r], 1);
                int row = rowbase + q * 4 + r;
                if ((lane & 1) == 0 && row < M)
                    ((unsigned*)g.outb[1])[(long)row * 64 + t * 8 + (c >> 1)] = pk2(acc[t][r], other);
            }
        // V pass
        #pragma unroll
        for (int t = 0; t < 8; ++t) {
            float b = g.bias2[t * 16 + c];
            acc[t] = (floatx4){b, b, b, b};
        }
        __syncthreads();
        #pragma unroll
        for (int t = 0; t < 8; ++t)
            #pragma unroll
            for (int s = 0; s < 4; ++s) {
                uint4 u = wlds[(t * 4 + s) * 64 + lane];
                acc[t] = __builtin_amdgcn_mfma_f32_16x16x32_bf16(af[s], *(short8*)&u, acc[t], 0, 0, 0);
            }
        #pragma unroll
        for (int t = 0; t < 8; ++t)
            #pragma unroll
            for (int r = 0; r < 4; ++r) {
                float other = __shfl_xor(acc[t][r], 1);
                int row = rowbase + q * 4 + r;
                if ((lane & 1) == 0 && row < M)
                    ((unsigned*)g.outb2)[(long)row * 64 + t * 8 + (c >> 1)] = pk2(acc[t][r], other);
            }
        return;
    }

    const int which = blockIdx.y;
    const int M = g.M[which];
    if ((int)blockIdx.x * 64 >= M) return;

    const float*          __restrict__ Af   = g.Af[which];
    const unsigned short* __restrict__ Ab   = g.Ab[which];
    const unsigned short* __restrict__ F    = g.F[which];
    const float*          __restrict__ bias = g.bias[which];
    const float bsc = g.bscale[which];
    float*          __restrict__ outf = g.outf[which];
    unsigned short* __restrict__ outb = g.outb[which];
    const int ostride = g.ostride[which];
    const int ooff    = g.ooff[which];
    const int rowbase = blockIdx.x * 64 + wave * 16;

    {
        const uint4* Fp = (const uint4*)F;
        #pragma unroll
        for (int j = 0; j < 8; ++j)
            wlds[threadIdx.x + j * 256] = Fp[threadIdx.x + j * 256];
    }

    int rowA = rowbase + c; if (rowA > M - 1) rowA = M - 1;
    short8 af[4];
    if (Af) {
        const float* Ar = Af + (long)rowA * DIMC + q * 8;
        #pragma unroll
        for (int s = 0; s < 4; ++s) {
            float4 x0 = *(const float4*)(Ar + s * 32);
            float4 x1 = *(const float4*)(Ar + s * 32 + 4);
            uint4 u;
            u.x = pk2(x0.x, x0.y);
            u.y = pk2(x0.z, x0.w);
            u.z = pk2(x1.x, x1.y);
            u.w = pk2(x1.z, x1.w);
            af[s] = *(short8*)&u;
        }
    } else {
        const unsigned short* Ar = Ab + (long)rowA * DIMC + q * 8;
        #pragma unroll
        for (int s = 0; s < 4; ++s) {
            uint4 u = *(const uint4*)(Ar + s * 32);
            af[s] = *(short8*)&u;
        }
    }

    floatx4 acc[8];
    #pragma unroll
    for (int t = 0; t < 8; ++t) {
        float b = bias ? bias[t * 16 + c] * bsc : 0.0f;
        acc[t] = (floatx4){b, b, b, b};
    }

    __syncthreads();

    #pragma unroll
    for (int t = 0; t < 8; ++t)
        #pragma unroll
        for (int s = 0; s < 4; ++s) {
            uint4 u = wlds[(t * 4 + s) * 64 + lane];
            acc[t] = __builtin_amdgcn_mfma_f32_16x16x32_bf16(af[s], *(short8*)&u, acc[t], 0, 0, 0);
        }

    if (outf) {
        #pragma unroll
        for (int t = 0; t < 8; ++t)
            #pragma unroll
            for (int r = 0; r < 4; ++r) {
                int row = rowbase + q * 4 + r;
                if (row < M)
                    outf[(long)row * DIMC + t * 16 + c] = acc[t][r];
            }
    } else {
        #pragma unroll
        for (int t = 0; t < 8; ++t)
            #pragma unroll
            for (int r = 0; r < 4; ++r) {
                float other = __shfl_xor(acc[t][r], 1);
                int row = rowbase + q * 4 + r;
                if ((lane & 1) == 0 && row < M) {
                    unsigned word = pk2(acc[t][r], other);
                    ((unsigned*)outb)[((long)row * 64 + t * 8 + (c >> 1))
                                      * (long)ostride + ooff] = word;
                }
            }
    }
}

// ---------------- CSR build ----------------
__global__ __launch_bounds__(256) void partial_sums(const int* __restrict__ deg,
                                                    int* __restrict__ partial, int N)
{
    __shared__ int sh[256];
    int t = threadIdx.x;
    int beg = blockIdx.x * 1024 + t * 4;
    int s = 0;
    if (beg + 3 < N) { int4 v = *(const int4*)(deg + beg); s = v.x + v.y + v.z + v.w; }
    else { for (int j = 0; j < 4; ++j) if (beg + j < N) s += deg[beg + j]; }
    sh[t] = s;
    __syncthreads();
    for (int d = 128; d >= 1; d >>= 1) {
        if (t < d) sh[t] += sh[t + d];
        __syncthreads();
    }
    if (t == 0) partial[blockIdx.x] = sh[0];
}

__global__ __launch_bounds__(256) void scan_write_offsets(const int* __restrict__ deg,
                                                          const int* __restrict__ partial,
                                                          int* __restrict__ offs,
                                                          int* __restrict__ cursor, int N, int nb)
{
    __shared__ int sh[256];
    __shared__ int sbase;
    int t = threadIdx.x;
    if (t < 64) {
        int v = (t < nb && t < (int)blockIdx.x) ? partial[t] : 0;
        #pragma unroll
        for (int d = 32; d >= 1; d >>= 1) v += __shfl_xor(v, d);
        if (t == 0) sbase = v;
    }
    int beg = blockIdx.x * 1024 + t * 4;
    int d0 = 0, d1 = 0, d2 = 0, d3 = 0;
    if (beg + 3 < N) { int4 v = *(const int4*)(deg + beg); d0 = v.x; d1 = v.y; d2 = v.z; d3 = v.w; }
    else {
        if (beg < N)     d0 = deg[beg];
        if (beg + 1 < N) d1 = deg[beg + 1];
        if (beg + 2 < N) d2 = deg[beg + 2];
        if (beg + 3 < N) d3 = deg[beg + 3];
    }
    int s = d0 + d1 + d2 + d3;
    sh[t] = s;
    __syncthreads();
    for (int d = 1; d < 256; d <<= 1) {
        int v = (t >= d) ? sh[t - d] : 0;
        __syncthreads();
        sh[t] += v;
        __syncthreads();
    }
    int base = sbase + sh[t] - s;
    int o0 = base, o1 = o0 + d0, o2 = o1 + d1, o3 = o2 + d2;
    if (beg < N)     { offs[beg]     = o0; cursor[beg]     = o0; }
    if (beg + 1 < N) { offs[beg + 1] = o1; cursor[beg + 1] = o1; }
    if (beg + 2 < N) { offs[beg + 2] = o2; cursor[beg + 2] = o2; }
    if (beg + 3 < N) { offs[beg + 3] = o3; cursor[beg + 3] = o3; }
}

__global__ void scatter_kernel(const int* __restrict__ src, const int* __restrict__ dst,
                               const int* __restrict__ etype, int* __restrict__ cursor,
                               int2* __restrict__ sedge, int E)
{
    int e = blockIdx.x * blockDim.x + threadIdx.x;
    if (e < E) {
        int d = dst[e];
        int p = atomicAdd(&cursor[d], 1);
        sedge[p] = make_int2(src[e] << 8, etype[e] << 9);
    }
}

// ---------------- per-node dual softmax + V aggregation ----------------
// wave = 1 node; QUARTER-wave (16 lanes) = 1 edge, lane owns 8 dims.
// One fully-coalesced 16B instruction per K/V table per edge; QK = 2x16B.
// Depth-1 sedge prefetch (8B) cuts the per-iter serial chain front.
// Self-loop = virtual edge at index dcnt. Q stored bf16 pre-scaled to exp2 domain.
__global__ __launch_bounds__(256) void node_kernel(
    const char*  __restrict__ Qb,     // row n at byte n<<8 (bf16); lane ql: 16B at ql<<4
    const char*  __restrict__ Kb,     // row n at byte n<<8; lane ql: 16B at ql<<4
    const char*  __restrict__ Vb,     // same layout as Kb
    const char*  __restrict__ QKb,    // row t at byte t<<9; lane ql: 32B at ql<<5
    const int* __restrict__ offs, const int* __restrict__ deg,
    const int2* __restrict__ sedge,   // (src<<8, type<<9)
    float* __restrict__ out_sta, uint4* __restrict__ feat_dyn,
    int N, int R)
{
    int n = (blockIdx.x * blockDim.x + threadIdx.x) >> 6;
    int lane = threadIdx.x & 63;
    if (n >= N) return;
    const int ql = lane & 15;    // lane within quarter
    const int qt = lane >> 4;    // quarter id (edge stream)
    const int lo16 = ql << 4;
    const int lo32 = ql << 5;

    int base = offs[n];
    int dcnt = deg[n];
    int etot = dcnt + 1;             // + virtual self edge at index dcnt

    // q dims 8ql..8ql+7 from bf16 row (pre-scaled)
    f32x2 qr0, qr1, qr2, qr3;
    {
        uint4 qw = *(const uint4*)(Qb + ((long)n << 8) + lo16);
        qr0 = bfp(qw.x); qr1 = bfp(qw.y); qr2 = bfp(qw.z); qr3 = bfp(qw.w);
    }

    float s_d = 0.0f, s_s = 0.0f;
    f32x2 accd0 = {0.f, 0.f}, accd1 = accd0, accd2 = accd0, accd3 = accd0;
    f32x2 accs0 = accd0, accs1 = accd0, accs2 = accd0, accs3 = accd0;

    const int2 eself = make_int2(n << 8, R << 9);

    int T = (etot + 3) >> 2;
    int2 eCur = eself;
    {
        int i = qt;
        if (i < dcnt) eCur = sedge[base + i];
    }
    for (int it = 0; it < T; ++it) {
        int i = 4 * it + qt;
        bool vv = i < etot;

        int2 eNxt = eself;
        if (it + 1 < T) {
            int inx = 4 * (it + 1) + qt;
            if (inx < dcnt) eNxt = sedge[base + inx];
        }

        uint4 kx  = *(const uint4*)(Kb + eCur.x + lo16);
        uint4 vx  = *(const uint4*)(Vb + eCur.x + lo16);
        uint4 qk0 = *(const uint4*)(QKb + eCur.y + lo32);
        uint4 qk1 = *(const uint4*)(QKb + eCur.y + lo32 + 16);

        f32x2 dp;
        dp  = (qr0 + bfp(qk0.x)) * (bfp(kx.x) + bfp(qk0.y));
        dp += (qr1 + bfp(qk0.z)) * (bfp(kx.y) + bfp(qk0.w));
        dp += (qr2 + bfp(qk1.x)) * (bfp(kx.z) + bfp(qk1.y));
        dp += (qr3 + bfp(qk1.z)) * (bfp(kx.w) + bfp(qk1.w));
        float p = red16(dp.x + dp.y);

        float wd = vv ? exp2f(p)  : 0.0f;
        float ws = vv ? exp2f(-p) : 0.0f;
        s_d += wd; s_s += ws;

        f32x2 v0 = bfp(vx.x), v1 = bfp(vx.y), v2 = bfp(vx.z), v3 = bfp(vx.w);
        accd0 += v0 * wd; accd1 += v1 * wd; accd2 += v2 * wd; accd3 += v3 * wd;
        accs0 += v0 * ws; accs1 += v1 * ws; accs2 += v2 * ws; accs3 += v3 * ws;

        eCur = eNxt;
    }

    // ---- merge quarters (plain sums; dims align across quarters via ql) ----
    #define MRG(x) { x += __shfl_xor(x, 16); x += __shfl_xor(x, 32); }
    MRG(s_d) MRG(s_s)
    MRG(accd0.x) MRG(accd0.y) MRG(accd1.x) MRG(accd1.y)
    MRG(accd2.x) MRG(accd2.y) MRG(accd3.x) MRG(accd3.y)
    MRG(accs0.x) MRG(accs0.y) MRG(accs1.x) MRG(accs1.y)
    MRG(accs2.x) MRG(accs2.y) MRG(accs3.x) MRG(accs3.y)
    #undef MRG

    if (qt == 0) {
        float denom = (float)(dcnt + 1);
        float id_ = 1.0f / (s_d * denom);
        float is_ = 1.0f / (s_s * denom);
        float4* op = (float4*)(out_sta + (long)n * DIMC + ql * 8);
        op[0] = make_float4(accs0.x * is_, accs0.y * is_, accs1.x * is_, accs1.y * is_);
        op[1] = make_float4(accs2.x * is_, accs2.y * is_, accs3.x * is_, accs3.y * is_);
        uint4 w;
        w.x = pk2(accd0.x * id_, accd0.y * id_);
        w.y = pk2(accd1.x * id_, accd1.y * id_);
        w.z = pk2(accd2.x * id_, accd2.y * id_);
        w.w = pk2(accd3.x * id_, accd3.y * id_);
        feat_dyn[(unsigned)n * 16u + ql] = w;
    }
}

// ---------------- launch ----------------
extern "C" void kernel_launch(void* const* d_in, const int* in_sizes, int n_in,
                              void* d_out, int out_size, void* d_ws, size_t ws_size,
                              hipStream_t stream)
{
    const float* curr    = (const float*)d_in[0];
    const float* last    = (const float*)d_in[1];
    const float* relemb  = (const float*)d_in[2];
    const float* selfrel = (const float*)d_in[3];
    const float* Wq      = (const float*)d_in[4];
    const float* bq      = (const float*)d_in[5];
    const float* Wk      = (const float*)d_in[6];
    const float* bk      = (const float*)d_in[7];
    const float* Wv      = (const float*)d_in[8];
    const float* bv      = (const float*)d_in[9];
    const float* dynw    = (const float*)d_in[10];
    const int*   eidx    = (const int*)d_in[11];
    const int*   etype   = (const int*)d_in[12];
    float* out = (float*)d_out;

    const int N = in_sizes[0] / DIMC;   // 40000
    const int E = in_sizes[12];         // 400000
    const int R = in_sizes[2] / DIMC;   // 502
    const int* esrc = eidx;
    const int* edst = eidx + E;

    char* wp = (char*)d_ws;
    auto alloc = [&](size_t bytes) { char* r = wp; wp += (bytes + 15) & ~(size_t)15; return r; };
    size_t nd = (size_t)N * DIMC;
    unsigned short* Qb    = (unsigned short*)alloc((size_t)N * 256);
    unsigned short* Kb    = (unsigned short*)alloc((size_t)N * 256);
    unsigned short* Vb    = (unsigned short*)alloc((size_t)N * 256);
    unsigned short* Fdb   = (unsigned short*)alloc(nd * 2);
    uint4*          QKre  = (uint4*)alloc((size_t)(R + 1) * 32 * 16);
    float*          TypeEmb = (float*)alloc((size_t)(R + 2) * DIMC * 4);
    unsigned short* FW[6];
    for (int m = 0; m < 6; ++m) FW[m] = (unsigned short*)alloc(2048 * 8 * 2);
    int*            deg   = (int*)alloc((size_t)N * 4);
    int*            offs  = (int*)alloc((size_t)N * 4);
    int*            cursor= (int*)alloc((size_t)N * 4);
    int2*           sedge = (int2*)alloc((size_t)E * 8);
    int*            partial = (int*)alloc(256 * 4);

    const int gblk = N / 64;                 // 625
    const int sblk = (N + 1023) / 1024;      // 40

    // 1. fused prep (also zeroes deg); Q-side weights pre-scaled by (1/sqrt(128))*log2(e)
    PrepArgs pa;
    pa.W[0] = Wq;   pa.W[1] = Wk;   pa.W[2] = Wv;
    pa.W[3] = dynw; pa.W[4] = Wq + (size_t)DIMC * DIMC; pa.W[5] = Wk + (size_t)DIMC * DIMC;
    pa.wscale[0] = CS2L; pa.wscale[1] = 1.0f; pa.wscale[2] = 1.0f;
    pa.wscale[3] = 1.0f; pa.wscale[4] = CS2L; pa.wscale[5] = 1.0f;
    for (int m = 0; m < 6; ++m) pa.F[m] = FW[m];
    pa.relemb = relemb; pa.selfrel = selfrel; pa.TypeEmb = TypeEmb;
    pa.deg = deg; pa.R = R; pa.N = N;
    int pgrid = 192 + (R + 1) + (N + 63) / 64;
    hipLaunchKernelGGL(prep_all, dim3(pgrid), dim3(64), 0, stream, pa);

    // 2. projections + histogram: y=0 Q(bf16), y=1 fused K+V, y=2/3 QK, y=4 hist
    GemmM5 g5;
    for (int s = 0; s < 5; ++s) { g5.Af[s] = nullptr; g5.Ab[s] = nullptr; g5.outf[s] = nullptr; g5.outb[s] = nullptr; g5.bias[s] = nullptr; g5.bscale[s] = 1.0f; g5.ostride[s] = 1; g5.ooff[s] = 0; g5.M[s] = 0; }
    g5.Af[0] = curr;    g5.F[0] = FW[0]; g5.outb[0] = Qb;  g5.M[0] = N;
    g5.Af[1] = last;    g5.F[1] = FW[1]; g5.outb[1] = Kb;  g5.M[1] = N;
    g5.F2 = FW[2]; g5.bias2 = bv; g5.outb2 = Vb;
    g5.Af[2] = TypeEmb; g5.F[2] = FW[4]; g5.bias[2] = bq;  g5.outb[2] = (unsigned short*)QKre;
    g5.ostride[2] = 2;  g5.ooff[2] = 0;  g5.M[2] = R + 1;  g5.bscale[2] = CS2L;
    g5.Af[3] = TypeEmb; g5.F[3] = FW[5]; g5.bias[3] = bk;  g5.outb[3] = (unsigned short*)QKre;
    g5.ostride[3] = 2;  g5.ooff[3] = 1;  g5.M[3] = R + 1;
    g5.hist_dst = edst; g5.hist_deg = deg; g5.hist_E = E;
    hipLaunchKernelGGL(gemm_mfma, dim3(gblk, 5), dim3(256), 0, stream, g5);

    // 3. CSR build
    hipLaunchKernelGGL(partial_sums, dim3(sblk), dim3(256), 0, stream, deg, partial, N);
    hipLaunchKernelGGL(scan_write_offsets, dim3(sblk), dim3(256), 0, stream,
                       deg, partial, offs, cursor, N, sblk);
    hipLaunchKernelGGL(scatter_kernel, dim3((E + 255) / 256), dim3(256), 0, stream,
                       esrc, edst, etype, cursor, sedge, E);

    // 4. node aggregation (4 nodes per 256-thread block; quarter-wave per edge)
    hipLaunchKernelGGL(node_kernel, dim3((N + 3) / 4), dim3(256), 0, stream,
                       (const char*)Qb, (const char*)Kb, (const char*)Vb, (const char*)QKre,
                       offs, deg, sedge, out, (uint4*)Fdb, N, R);

    // 5. final GEMM: feat_dyn @ dyn_weight
    GemmM5 gf;
    for (int s = 0; s < 5; ++s) { gf.Af[s] = nullptr; gf.Ab[s] = nullptr; gf.outf[s] = nullptr; gf.outb[s] = nullptr; gf.bias[s] = nullptr; gf.bscale[s] = 1.0f; gf.ostride[s] = 1; gf.ooff[s] = 0; gf.M[s] = 0; }
    gf.Ab[0] = Fdb; gf.F[0] = FW[3]; gf.outf[0] = out + nd; gf.M[0] = N;
    gf.F2 = FW[2]; gf.bias2 = bv; gf.outb2 = Vb;
    gf.hist_dst = edst; gf.hist_deg = deg; gf.hist_E = 0;
    hipLaunchKernelGGL(gemm_mfma, dim3(gblk, 1), dim3(256), 0, stream, gf);
}